// Round 6
// baseline (217.553 us; speedup 1.0000x reference)
//
#include <hip/hip_runtime.h>
#include <stdint.h>

// ---- problem constants ----
#define Bz 8
#define Tz 1024
#define Cz 768
#define Hz 8
#define Dz 96
#define BHz 64            // Bz*Hz
#define Kz 768

typedef __bf16 bf16x8 __attribute__((ext_vector_type(8)));
typedef unsigned short u16x8 __attribute__((ext_vector_type(8)));
typedef float f32x4 __attribute__((ext_vector_type(4)));

__device__ __forceinline__ unsigned short f2bf(float f) {
  union { float f; unsigned int u; } v; v.f = f;
  unsigned int u = v.u;
  return (unsigned short)((u + 0x7fffu + ((u >> 16) & 1u)) >> 16);
}

// pack two f32 -> one dword of 2x bf16 (lo=a, hi=b); gfx950 hw instr (guide T12, m214v22)
__device__ __forceinline__ unsigned int cvtpk(float a, float b) {
  unsigned int r;
  asm("v_cvt_pk_bf16_f32 %0, %1, %2" : "=v"(r) : "v"(a), "v"(b));
  return r;
}

#if defined(__has_builtin)
#if __has_builtin(__builtin_amdgcn_exp2f)
#define EXP2(x) __builtin_amdgcn_exp2f(x)
#endif
#endif
#ifndef EXP2
#define EXP2(x) __expf((x) * 0.6931471805599453f)
#endif

// async global->LDS, 16B per lane; LDS dest must be wave-uniform base (+lane*16 implicit)
typedef const __attribute__((address_space(1))) void* gas_ptr;
typedef __attribute__((address_space(3))) void* las_ptr;
__device__ __forceinline__ void gl16(const void* g, void* l) {
  __builtin_amdgcn_global_load_lds((gas_ptr)g, (las_ptr)l, 16, 0, 0);
}

// ---- cast x (fp32) -> bf16, 4 elems/thread ----
__global__ __launch_bounds__(256) void cast_f32_bf16(const float* __restrict__ in,
                                                     unsigned short* __restrict__ out) {
  int i = (blockIdx.x * 256 + threadIdx.x) * 4;
  float4 v = *(const float4*)(in + i);
  union { unsigned short s[4]; uint2 u; } o;
  o.s[0] = f2bf(v.x); o.s[1] = f2bf(v.y); o.s[2] = f2bf(v.z); o.s[3] = f2bf(v.w);
  *(uint2*)(out + i) = o.u;
}

// ---- transpose + cast: in[R][Cc] fp32 -> out[Cc][R] bf16 ----
__global__ __launch_bounds__(256) void transpose_cast(const float* __restrict__ in,
                                                      unsigned short* __restrict__ out,
                                                      int R, int Cc) {
  __shared__ unsigned short t[64][72];
  int bx = blockIdx.x * 64;   // col base of in
  int by = blockIdx.y * 64;   // row base of in
  int tid = threadIdx.x;
#pragma unroll
  for (int i = 0; i < 16; i++) {
    int idx = tid + i * 256;
    int r = idx >> 6, c = idx & 63;
    t[c][r] = f2bf(in[(by + r) * Cc + bx + c]);
  }
  __syncthreads();
#pragma unroll
  for (int i = 0; i < 16; i++) {
    int idx = tid + i * 256;
    int r = idx >> 6, c = idx & 63;
    out[(bx + r) * R + by + c] = t[r][c];
  }
}

// ---- 128x128 MFMA bf16 GEMM with global_load_lds staging (m97 structure) ----
// Natural block mapping (bm=bx, bn=by): HW round-robin dispatch gives XCD x
// bm in {x, x+8, ...} for every bn -> per-XCD A working set 1.57 MB (L2-resident).
// Round-4 lesson: a contiguous-chunk XCD swizzle DESTROYED this (FETCH 89 MB, +13us).
// MODE 0: epilogue scatters bf16 into qkv: Q,K as [which][64][1024][96];
//         V third written TRANSPOSED as [64][96][1024] (V^T).
// MODE 1: epilogue writes fp32 C[M][768]
template <int MODE>
__global__ __launch_bounds__(256)
void gemm128(const unsigned short* __restrict__ A,
             const unsigned short* __restrict__ Bt,
             unsigned short* __restrict__ obf,
             float* __restrict__ of32) {
  __shared__ unsigned short Asm[128 * 32];  // unpadded: required by global_load_lds lane order
  __shared__ unsigned short Bsm[128 * 32];
  const int tid = threadIdx.x;
  const int wave = tid >> 6, lane = tid & 63;
  const int quad = lane >> 4, l16 = lane & 15;
  const int bm = blockIdx.x, bn = blockIdx.y;
  const int wm = (wave >> 1) * 64, wn = (wave & 1) * 64;

  f32x4 zero = {0.f, 0.f, 0.f, 0.f};
  f32x4 acc[4][4];
#pragma unroll
  for (int i = 0; i < 4; i++)
#pragma unroll
    for (int j = 0; j < 4; j++) acc[i][j] = zero;

  // staging map: wave w issue q covers rows w*32+q*16 .. +15; lane l -> row +(l>>2), k-part (l&3)*8
  const int rr = lane >> 2, c8 = (lane & 3) * 8;
  const unsigned short* Ag0 = A + (size_t)(bm * 128 + wave * 32 + rr) * Kz + c8;
  const unsigned short* Ag1 = Ag0 + 16 * Kz;
  const unsigned short* Bg0 = Bt + (size_t)(bn * 128 + wave * 32 + rr) * Kz + c8;
  const unsigned short* Bg1 = Bg0 + 16 * Kz;
  unsigned short* lA0 = &Asm[wave * 1024];      // elements; bytes = wave*2048
  unsigned short* lA1 = lA0 + 512;
  unsigned short* lB0 = &Bsm[wave * 1024];
  unsigned short* lB1 = lB0 + 512;

  for (int k0 = 0; k0 < Kz; k0 += 32) {
    __syncthreads();                 // WAR: previous frag reads done
    gl16(Ag0 + k0, lA0);
    gl16(Ag1 + k0, lA1);
    gl16(Bg0 + k0, lB0);
    gl16(Bg1 + k0, lB1);
    __syncthreads();                 // drains vmcnt(0) then barrier
    bf16x8 af[4], bfr[4];
#pragma unroll
    for (int mi = 0; mi < 4; mi++)
      af[mi] = *(const bf16x8*)&Asm[(wm + mi * 16 + l16) * 32 + quad * 8];
#pragma unroll
    for (int ni = 0; ni < 4; ni++)
      bfr[ni] = *(const bf16x8*)&Bsm[(wn + ni * 16 + l16) * 32 + quad * 8];
#pragma unroll
    for (int mi = 0; mi < 4; mi++)
#pragma unroll
      for (int ni = 0; ni < 4; ni++)
        acc[mi][ni] = __builtin_amdgcn_mfma_f32_16x16x32_bf16(af[mi], bfr[ni], acc[mi][ni], 0, 0, 0);
  }

#pragma unroll
  for (int mi = 0; mi < 4; mi++) {
    int row = bm * 128 + wm + mi * 16 + quad * 4;
    if (MODE == 0) {
      int b = row >> 10;
      int t = row & 1023;
#pragma unroll
      for (int ni = 0; ni < 4; ni++) {
        int col = bn * 128 + wn + ni * 16 + l16;
        int which = col / 768;        // wave-uniform per fragment (16 | 768)
        int cc = col - which * 768;
        int h = cc / 96;
        int d = cc - h * 96;
        if (which == 2) {
          // V^T layout: [bh][d][t]; r increments t -> 4 contiguous bf16 = one 8B store
          int base = ((2 * 64 + b * 8 + h) * 96 + d) * 1024 + t;
          union { unsigned short s[4]; uint2 u; } o;
#pragma unroll
          for (int r = 0; r < 4; r++) o.s[r] = f2bf(acc[mi][ni][r]);
          *(uint2*)(obf + base) = o.u;
        } else {
          int base = ((which * 64 + b * 8 + h) * 1024 + t) * 96 + d;
#pragma unroll
          for (int r = 0; r < 4; r++) obf[base + r * 96] = f2bf(acc[mi][ni][r]);
        }
      }
    } else {
#pragma unroll
      for (int ni = 0; ni < 4; ni++) {
        int col = bn * 128 + wn + ni * 16 + l16;
#pragma unroll
        for (int r = 0; r < 4; r++) of32[(row + r) * 768 + col] = acc[mi][ni][r];
      }
    }
  }
}

// ---- flash attention: 1 block = (b,h) x 64 q-rows; 4 waves x 16 rows; BS=128 ----
// Round 6: swapped QK^T (mfma(K,Q) -> S^T) makes each lane hold 32 P-values of ONE
// q-row (q = l16): softmax state is scalar/lane, row-max reduce = 2 shfl, P packs
// in-register via v_cvt_pk_bf16_f32 and reroutes to the PV A-fragment with a
// 2-stage shfl_xor butterfly — Psm (and its 32 ds_write + 8 ds_read / iter) deleted.
// LDS 26.1KB -> 4 blocks/CU.
__global__ __launch_bounds__(256, 4)
void attn(const unsigned short* __restrict__ qkv, unsigned short* __restrict__ y) {
  const int bh = blockIdx.x;
  const int by = blockIdx.y;
  const int q0 = (15 - by) * 64;           // heavy tiles dispatch first, class-balanced
  const int tid = threadIdx.x;
  const int wave = tid >> 6, lane = tid & 63;
  const int quad = lane >> 4, l16 = lane & 15;
  const int qw0 = q0 + wave * 16;          // this wave's 16 q-rows (1 m-tile)
  const int b = bh >> 3, h = bh & 7;

  const unsigned short* Qh = qkv + bh * Tz * Dz;
  const unsigned short* Kh = qkv + (BHz + bh) * Tz * Dz;
  const unsigned short* Vt = qkv + 2 * BHz * Tz * Dz + bh * Dz * Tz;  // V^T [d][t]

  __shared__ unsigned short Vsm[96 * 136];       // V^T [d][s], stride 136 (26112 B)

  // V staging thread map: round g covers rows g*16 + (tid>>4), 16B chunk tid&15
  const int vd = tid >> 4;
  const int vc = tid & 15;

  bf16x8 aq[3];                            // Q as MFMA B-operand: lane holds Q[q=l16][d..]
#pragma unroll
  for (int kd = 0; kd < 3; kd++)
    aq[kd] = *(const bf16x8*)(Qh + (qw0 + l16) * Dz + kd * 32 + quad * 8);

  f32x4 zero = {0.f, 0.f, 0.f, 0.f};
  f32x4 acc_o[6];
#pragma unroll
  for (int i = 0; i < 6; i++) acc_o[i] = zero;
  const float NEG = -__builtin_inff();
  float mrow = NEG, lrow = 0.f;            // scalar/lane: state of q-row (qw0 + l16)
  const float cs = 0.14724538519872735f;   // (1/sqrt(96)) * log2(e): exp2-domain softmax
  const int t_abs = qw0 + l16;             // this lane's q-row

  const int s_last = (q0 >> 7) << 7;       // floor(q0/128)*128
  for (int s0 = 0; s0 <= s_last; s0 += 128) {
    // ---- T14 issue-early: V^T tile global->reg; latency hides under QK^T+softmax ----
    u16x8 vreg[6];
#pragma unroll
    for (int g = 0; g < 6; g++)
      vreg[g] = *(const u16x8*)(Vt + (g * 16 + vd) * Tz + s0 + vc * 8);

    const int srem = qw0 + 15 - s0;              // >= 15 always; srem%16==15
    const int nlim = min(7, srem >> 4);          // last 16-wide s tile with unmasked cols
    const int klim = min(3, srem >> 5);          // last 32-wide PV k chunk

    // ---- S^T = K Q^T (swapped operands; lane holds S[s=quad*4+r][q=l16]) ----
    f32x4 sacc[8];
#pragma unroll
    for (int ni = 0; ni < 8; ni++) {
      if (ni <= nlim) {
        sacc[ni] = zero;
#pragma unroll
        for (int kd = 0; kd < 3; kd++) {
          bf16x8 bk = *(const bf16x8*)(Kh + (s0 + ni * 16 + l16) * Dz + kd * 32 + quad * 8);
          sacc[ni] = __builtin_amdgcn_mfma_f32_16x16x32_bf16(bk, aq[kd], sacc[ni], 0, 0, 0);
        }
      }
    }

    // ---- online softmax, fully in-register ----
    float rmx[4] = {NEG, NEG, NEG, NEG};         // 4 independent chains for ILP
#pragma unroll
    for (int ni = 0; ni < 8; ni++) {
      if (ni <= nlim) {
        // mask only tiles that straddle/cross the diagonal (wave-uniform test)
        if (s0 + ni * 16 + 15 > qw0) {
          const int s_base = s0 + ni * 16 + quad * 4;
#pragma unroll
          for (int r = 0; r < 4; r++)
            if (s_base + r > t_abs) sacc[ni][r] = NEG;
        }
#pragma unroll
        for (int r = 0; r < 4; r++) rmx[r] = fmaxf(rmx[r], sacc[ni][r]);
      }
    }
    float rmax = fmaxf(fmaxf(rmx[0], rmx[1]), fmaxf(rmx[2], rmx[3]));
    rmax = fmaxf(rmax, __shfl_xor(rmax, 16));    // quad-partner reduce: full row max
    rmax = fmaxf(rmax, __shfl_xor(rmax, 32));

    // deferred rescale (T13): 54 raw ~= 8 exp2-units -> p bounded by 2^8
    int ok = (rmax <= mrow + 54.0f) ? 1 : 0;
    if (!__all(ok)) {
      float mnew = fmaxf(mrow, rmax);
      float alpha = EXP2((mrow - mnew) * cs);    // m=-inf -> alpha=0 first iter
      mrow = mnew;
      lrow *= alpha;
      float av[4];
#pragma unroll
      for (int r = 0; r < 4; r++) av[r] = __shfl(alpha, quad * 4 + r);  // acc_o row = quad*4+r
#pragma unroll
      for (int di = 0; di < 6; di++)
#pragma unroll
        for (int r = 0; r < 4; r++) acc_o[di][r] *= av[r];
    }

    const float nmc = -mrow * cs;
    float rs[4] = {0.f, 0.f, 0.f, 0.f};
    unsigned int pk[8][2];                       // packed bf16x2: tile ni, s pairs
#pragma unroll
    for (int ni = 0; ni < 8; ni++) {
      if (ni <= nlim) {
        float p0 = EXP2(fmaf(sacc[ni][0], cs, nmc));   // masked: exp2(-inf)=0
        float p1 = EXP2(fmaf(sacc[ni][1], cs, nmc));
        float p2 = EXP2(fmaf(sacc[ni][2], cs, nmc));
        float p3 = EXP2(fmaf(sacc[ni][3], cs, nmc));
        rs[0] += p0; rs[1] += p1; rs[2] += p2; rs[3] += p3;
        pk[ni][0] = cvtpk(p0, p1);
        pk[ni][1] = cvtpk(p2, p3);
      } else {
        pk[ni][0] = 0u; pk[ni][1] = 0u;
      }
    }
    lrow += (rs[0] + rs[1]) + (rs[2] + rs[3]);   // per-lane partial; reduce at end

    // ---- T14 write-late: V regs -> LDS after WAR barrier (vectorized b128) ----
    __syncthreads();                 // prior iter's Vsm reads done
#pragma unroll
    for (int g = 0; g < 6; g++)
      *(u16x8*)&Vsm[(g * 16 + vd) * 136 + vc * 8] = vreg[g];
    __syncthreads();                 // Vsm ready

    // ---- O += P V : A-fragment built in-register via 2-stage butterfly ----
    // target quad q' needs s-chunk q'*8..q'*8+7 of the 32-s chunk kc:
    //   q0 <- {q0.a, q1.a}; q1 <- {q2.a, q3.a}; q2 <- {q0.b, q1.b}; q3 <- {q2.b, q3.b}
    // (a = tile 2kc, b = tile 2kc+1; each source quad holds 2 dwords = 4 s-values)
#pragma unroll
    for (int kc = 0; kc < 4; kc++) {
      if (kc <= klim) {
        const unsigned int a0 = pk[2 * kc][0], a1 = pk[2 * kc][1];
        const unsigned int b0 = pk[2 * kc + 1][0], b1 = pk[2 * kc + 1][1];
        // stage 1 (xor 32): quads 0,1 receive partner's a; quads 2,3 receive partner's b
        const unsigned int s0w = (quad < 2) ? b0 : a0;
        const unsigned int s1w = (quad < 2) ? b1 : a1;
        const unsigned int u0 = (unsigned int)__shfl_xor((int)s0w, 32);
        const unsigned int u1 = (unsigned int)__shfl_xor((int)s1w, 32);
        // stage 2 (xor 16): quads 0,3 forward u; quad 1 sends own a, quad 2 sends own b
        const unsigned int t0w = (quad == 0 || quad == 3) ? u0 : ((quad == 1) ? a0 : b0);
        const unsigned int t1w = (quad == 0 || quad == 3) ? u1 : ((quad == 1) ? a1 : b1);
        const unsigned int r0 = (unsigned int)__shfl_xor((int)t0w, 16);
        const unsigned int r1 = (unsigned int)__shfl_xor((int)t1w, 16);
        // assemble per-quad: q0:{a,r} q1:{r,u} q2:{u,r} q3:{r,b}
        union { unsigned int w[4]; bf16x8 v; } ap;
        ap.w[0] = (quad == 0) ? a0 : ((quad == 2) ? u0 : r0);
        ap.w[1] = (quad == 0) ? a1 : ((quad == 2) ? u1 : r1);
        ap.w[2] = (quad == 0) ? r0 : ((quad == 1) ? u0 : ((quad == 2) ? r0 : b0));
        ap.w[3] = (quad == 0) ? r1 : ((quad == 1) ? u1 : ((quad == 2) ? r1 : b1));
#pragma unroll
        for (int di = 0; di < 6; di++) {
          bf16x8 bv = *(const bf16x8*)&Vsm[(di * 16 + l16) * 136 + kc * 32 + quad * 8];
          acc_o[di] = __builtin_amdgcn_mfma_f32_16x16x32_bf16(ap.v, bv, acc_o[di], 0, 0, 0);
        }
      }
    }
  }

  // ---- epilogue: reduce l across quad-partners, normalize, store ----
  lrow += __shfl_xor(lrow, 16);
  lrow += __shfl_xor(lrow, 32);              // lane holds full sum of its q-row
  float linv = 1.f / lrow;
  float lv[4];
#pragma unroll
  for (int r = 0; r < 4; r++) lv[r] = __shfl(linv, quad * 4 + r);
#pragma unroll
  for (int r = 0; r < 4; r++) {
    int t = qw0 + quad * 4 + r;
#pragma unroll
    for (int di = 0; di < 6; di++) {
      int d = di * 16 + l16;
      y[(b * Tz + t) * Cz + h * Dz + d] = f2bf(acc_o[di][r] * lv[r]);
    }
  }
}

// ---- workspace layout (bytes) ----
#define OFF_XB   0u
#define OFF_WAT  12582912u            // 8192*768*2
#define OFF_WPT  16121856u            // + 2304*768*2
#define OFF_QKV  17301504u            // + 768*768*2
#define OFF_Y    55050240u            // + 3*64*1024*96*2

extern "C" void kernel_launch(void* const* d_in, const int* in_sizes, int n_in,
                              void* d_out, int out_size, void* d_ws, size_t ws_size,
                              hipStream_t stream) {
  const float* x  = (const float*)d_in[0];
  const float* Wa = (const float*)d_in[1];
  const float* Wp = (const float*)d_in[2];
  float* out = (float*)d_out;
  uint8_t* ws = (uint8_t*)d_ws;
  unsigned short* xb  = (unsigned short*)(ws + OFF_XB);
  unsigned short* Wat = (unsigned short*)(ws + OFF_WAT);
  unsigned short* Wpt = (unsigned short*)(ws + OFF_WPT);
  unsigned short* qkv = (unsigned short*)(ws + OFF_QKV);
  unsigned short* y   = (unsigned short*)(ws + OFF_Y);

  cast_f32_bf16<<<6144, 256, 0, stream>>>(x, xb);
  transpose_cast<<<dim3(36, 12), 256, 0, stream>>>(Wa, Wat, 768, 2304);
  transpose_cast<<<dim3(12, 12), 256, 0, stream>>>(Wp, Wpt, 768, 768);
  gemm128<0><<<dim3(64, 18), 256, 0, stream>>>(xb, Wat, qkv, nullptr);
  attn<<<dim3(64, 16), 256, 0, stream>>>(qkv, y);
  gemm128<1><<<dim3(64, 6), 256, 0, stream>>>(y, Wpt, nullptr, out);
}

// Round 7
// 205.337 us; speedup vs baseline: 1.0595x; 1.0595x over previous
//
#include <hip/hip_runtime.h>
#include <stdint.h>

// ---- problem constants ----
#define Bz 8
#define Tz 1024
#define Cz 768
#define Hz 8
#define Dz 96
#define BHz 64            // Bz*Hz
#define Kz 768

typedef __bf16 bf16x8 __attribute__((ext_vector_type(8)));
typedef unsigned short u16x8 __attribute__((ext_vector_type(8)));
typedef float f32x4 __attribute__((ext_vector_type(4)));

__device__ __forceinline__ unsigned short f2bf(float f) {
  union { float f; unsigned int u; } v; v.f = f;
  unsigned int u = v.u;
  return (unsigned short)((u + 0x7fffu + ((u >> 16) & 1u)) >> 16);
}

// pack two f32 -> one dword of 2x bf16 (lo=a, hi=b); gfx950 hw instr (guide T12)
__device__ __forceinline__ unsigned int cvtpk(float a, float b) {
  unsigned int r;
  asm("v_cvt_pk_bf16_f32 %0, %1, %2" : "=v"(r) : "v"(a), "v"(b));
  return r;
}

#if defined(__has_builtin)
#if __has_builtin(__builtin_amdgcn_exp2f)
#define EXP2(x) __builtin_amdgcn_exp2f(x)
#endif
#endif
#ifndef EXP2
#define EXP2(x) __expf((x) * 0.6931471805599453f)
#endif

// async global->LDS, 16B per lane; LDS dest must be wave-uniform base (+lane*16 implicit)
typedef const __attribute__((address_space(1))) void* gas_ptr;
typedef __attribute__((address_space(3))) void* las_ptr;
__device__ __forceinline__ void gl16(const void* g, void* l) {
  __builtin_amdgcn_global_load_lds((gas_ptr)g, (las_ptr)l, 16, 0, 0);
}

// ---- cast x (fp32) -> bf16, 4 elems/thread ----
__global__ __launch_bounds__(256) void cast_f32_bf16(const float* __restrict__ in,
                                                     unsigned short* __restrict__ out) {
  int i = (blockIdx.x * 256 + threadIdx.x) * 4;
  float4 v = *(const float4*)(in + i);
  union { unsigned short s[4]; uint2 u; } o;
  o.s[0] = f2bf(v.x); o.s[1] = f2bf(v.y); o.s[2] = f2bf(v.z); o.s[3] = f2bf(v.w);
  *(uint2*)(out + i) = o.u;
}

// ---- transpose + cast: in[R][Cc] fp32 -> out[Cc][R] bf16 ----
__global__ __launch_bounds__(256) void transpose_cast(const float* __restrict__ in,
                                                      unsigned short* __restrict__ out,
                                                      int R, int Cc) {
  __shared__ unsigned short t[64][72];
  int bx = blockIdx.x * 64;   // col base of in
  int by = blockIdx.y * 64;   // row base of in
  int tid = threadIdx.x;
#pragma unroll
  for (int i = 0; i < 16; i++) {
    int idx = tid + i * 256;
    int r = idx >> 6, c = idx & 63;
    t[c][r] = f2bf(in[(by + r) * Cc + bx + c]);
  }
  __syncthreads();
#pragma unroll
  for (int i = 0; i < 16; i++) {
    int idx = tid + i * 256;
    int r = idx >> 6, c = idx & 63;
    out[(bx + r) * R + by + c] = t[r][c];
  }
}

// ---- 128x128 MFMA bf16 GEMM with global_load_lds staging (m97 structure) ----
// Natural block mapping (bm=bx, bn=by): HW round-robin dispatch gives XCD x
// bm in {x, x+8, ...} for every bn -> per-XCD A working set 1.57 MB (L2-resident).
// Round-4 lesson: a contiguous-chunk XCD swizzle DESTROYED this (FETCH 89 MB, +13us).
// MODE 0: epilogue scatters bf16 into qkv: Q,K as [which][64][1024][96];
//         V third written TRANSPOSED as [64][96][1024] (V^T).
// MODE 1: epilogue writes fp32 C[M][768]
template <int MODE>
__global__ __launch_bounds__(256)
void gemm128(const unsigned short* __restrict__ A,
             const unsigned short* __restrict__ Bt,
             unsigned short* __restrict__ obf,
             float* __restrict__ of32) {
  __shared__ unsigned short Asm[128 * 32];  // unpadded: required by global_load_lds lane order
  __shared__ unsigned short Bsm[128 * 32];
  const int tid = threadIdx.x;
  const int wave = tid >> 6, lane = tid & 63;
  const int quad = lane >> 4, l16 = lane & 15;
  const int bm = blockIdx.x, bn = blockIdx.y;
  const int wm = (wave >> 1) * 64, wn = (wave & 1) * 64;

  f32x4 zero = {0.f, 0.f, 0.f, 0.f};
  f32x4 acc[4][4];
#pragma unroll
  for (int i = 0; i < 4; i++)
#pragma unroll
    for (int j = 0; j < 4; j++) acc[i][j] = zero;

  // staging map: wave w issue q covers rows w*32+q*16 .. +15; lane l -> row +(l>>2), k-part (l&3)*8
  const int rr = lane >> 2, c8 = (lane & 3) * 8;
  const unsigned short* Ag0 = A + (size_t)(bm * 128 + wave * 32 + rr) * Kz + c8;
  const unsigned short* Ag1 = Ag0 + 16 * Kz;
  const unsigned short* Bg0 = Bt + (size_t)(bn * 128 + wave * 32 + rr) * Kz + c8;
  const unsigned short* Bg1 = Bg0 + 16 * Kz;
  unsigned short* lA0 = &Asm[wave * 1024];      // elements; bytes = wave*2048
  unsigned short* lA1 = lA0 + 512;
  unsigned short* lB0 = &Bsm[wave * 1024];
  unsigned short* lB1 = lB0 + 512;

  for (int k0 = 0; k0 < Kz; k0 += 32) {
    __syncthreads();                 // WAR: previous frag reads done
    gl16(Ag0 + k0, lA0);
    gl16(Ag1 + k0, lA1);
    gl16(Bg0 + k0, lB0);
    gl16(Bg1 + k0, lB1);
    __syncthreads();                 // drains vmcnt(0) then barrier
    bf16x8 af[4], bfr[4];
#pragma unroll
    for (int mi = 0; mi < 4; mi++)
      af[mi] = *(const bf16x8*)&Asm[(wm + mi * 16 + l16) * 32 + quad * 8];
#pragma unroll
    for (int ni = 0; ni < 4; ni++)
      bfr[ni] = *(const bf16x8*)&Bsm[(wn + ni * 16 + l16) * 32 + quad * 8];
#pragma unroll
    for (int mi = 0; mi < 4; mi++)
#pragma unroll
      for (int ni = 0; ni < 4; ni++)
        acc[mi][ni] = __builtin_amdgcn_mfma_f32_16x16x32_bf16(af[mi], bfr[ni], acc[mi][ni], 0, 0, 0);
  }

#pragma unroll
  for (int mi = 0; mi < 4; mi++) {
    int row = bm * 128 + wm + mi * 16 + quad * 4;
    if (MODE == 0) {
      int b = row >> 10;
      int t = row & 1023;
#pragma unroll
      for (int ni = 0; ni < 4; ni++) {
        int col = bn * 128 + wn + ni * 16 + l16;
        int which = col / 768;        // wave-uniform per fragment (16 | 768)
        int cc = col - which * 768;
        int h = cc / 96;
        int d = cc - h * 96;
        if (which == 2) {
          // V^T layout: [bh][d][t]; r increments t -> 4 contiguous bf16 = one 8B store
          int base = ((2 * 64 + b * 8 + h) * 96 + d) * 1024 + t;
          union { unsigned short s[4]; uint2 u; } o;
#pragma unroll
          for (int r = 0; r < 4; r++) o.s[r] = f2bf(acc[mi][ni][r]);
          *(uint2*)(obf + base) = o.u;
        } else {
          int base = ((which * 64 + b * 8 + h) * 1024 + t) * 96 + d;
#pragma unroll
          for (int r = 0; r < 4; r++) obf[base + r * 96] = f2bf(acc[mi][ni][r]);
        }
      }
    } else {
#pragma unroll
      for (int ni = 0; ni < 4; ni++) {
        int col = bn * 128 + wn + ni * 16 + l16;
#pragma unroll
        for (int r = 0; r < 4; r++) of32[(row + r) * 768 + col] = acc[mi][ni][r];
      }
    }
  }
}

// ---- flash attention: 1 block = (b,h) x 64 q-rows; 4 waves x 16 rows; BS=128 ----
// Round 7: round-6 swapped-QK^T in-register-P structure, register pressure fixed:
// V staged via global_load_lds DIRECT into linear Vsm[96][128] (no vreg, no ds_write,
// -24 VGPR). Rule-21 both-sides swizzle: global source chunk pre-XORed with row&7,
// PV read applies the same XOR -> 2 lanes/bank (free). gl16 issued at iter top,
// drained by the pre-PV __syncthreads (vmcnt(0)) => T14-style overlap for free.
__global__ __launch_bounds__(256, 4)
void attn(const unsigned short* __restrict__ qkv, unsigned short* __restrict__ y) {
  const int bh = blockIdx.x;
  const int by = blockIdx.y;
  const int q0 = (15 - by) * 64;           // heavy tiles dispatch first, class-balanced
  const int tid = threadIdx.x;
  const int wave = tid >> 6, lane = tid & 63;
  const int quad = lane >> 4, l16 = lane & 15;
  const int qw0 = q0 + wave * 16;          // this wave's 16 q-rows (1 m-tile)
  const int b = bh >> 3, h = bh & 7;

  const unsigned short* Qh = qkv + bh * Tz * Dz;
  const unsigned short* Kh = qkv + (BHz + bh) * Tz * Dz;
  const unsigned short* Vt = qkv + 2 * BHz * Tz * Dz + bh * Dz * Tz;  // V^T [d][t]

  __shared__ unsigned short Vsm[96 * 128];       // linear (gl16 dest), source-swizzled

  bf16x8 aq[3];                            // Q as MFMA B-operand: lane holds Q[q=l16][d..]
#pragma unroll
  for (int kd = 0; kd < 3; kd++)
    aq[kd] = *(const bf16x8*)(Qh + (qw0 + l16) * Dz + kd * 32 + quad * 8);

  f32x4 zero = {0.f, 0.f, 0.f, 0.f};
  f32x4 acc_o[6];
#pragma unroll
  for (int i = 0; i < 6; i++) acc_o[i] = zero;
  const float NEG = -__builtin_inff();
  float mrow = NEG, lrow = 0.f;            // scalar/lane: state of q-row (qw0 + l16)
  const float cs = 0.14724538519872735f;   // (1/sqrt(96)) * log2(e): exp2-domain softmax
  const int t_abs = qw0 + l16;             // this lane's q-row

  // V staging map (per wave-issue g): rows (wave*6+g)*4 .. +3, lane -> row +(lane>>4),
  // chunk lane&15; global source chunk pre-swizzled: c ^ (row&7)
  const int vrow = wave * 24 + (lane >> 4);      // row of THIS lane at g=0 (g adds 4)
  const int vch = lane & 15;

  const int s_last = (q0 >> 7) << 7;       // floor(q0/128)*128
  for (int s0 = 0; s0 <= s_last; s0 += 128) {
    __syncthreads();                 // WAR: prior iter's Vsm reads done
    // ---- async V^T tile -> LDS (drains at the pre-PV barrier; hides under QK^T) ----
#pragma unroll
    for (int g = 0; g < 6; g++) {
      const int row = vrow + g * 4;
      gl16(Vt + row * Tz + s0 + ((vch ^ (row & 7)) << 3),
           &Vsm[(wave * 24 + g * 4) * 128]);
    }

    const int srem = qw0 + 15 - s0;              // >= 15 always; srem%16==15
    const int nlim = min(7, srem >> 4);          // last 16-wide s tile with unmasked cols
    const int klim = min(3, srem >> 5);          // last 32-wide PV k chunk

    // ---- S^T = K Q^T (swapped operands; lane holds S[s=quad*4+r][q=l16]) ----
    f32x4 sacc[8];
#pragma unroll
    for (int ni = 0; ni < 8; ni++) {
      if (ni <= nlim) {
        sacc[ni] = zero;
#pragma unroll
        for (int kd = 0; kd < 3; kd++) {
          bf16x8 bk = *(const bf16x8*)(Kh + (s0 + ni * 16 + l16) * Dz + kd * 32 + quad * 8);
          sacc[ni] = __builtin_amdgcn_mfma_f32_16x16x32_bf16(bk, aq[kd], sacc[ni], 0, 0, 0);
        }
      }
    }

    // ---- online softmax, fully in-register ----
    float rmx[4] = {NEG, NEG, NEG, NEG};         // 4 independent chains for ILP
#pragma unroll
    for (int ni = 0; ni < 8; ni++) {
      if (ni <= nlim) {
        // mask only tiles that straddle/cross the diagonal (wave-uniform test)
        if (s0 + ni * 16 + 15 > qw0) {
          const int s_base = s0 + ni * 16 + quad * 4;
#pragma unroll
          for (int r = 0; r < 4; r++)
            if (s_base + r > t_abs) sacc[ni][r] = NEG;
        }
#pragma unroll
        for (int r = 0; r < 4; r++) rmx[r] = fmaxf(rmx[r], sacc[ni][r]);
      }
    }
    float rmax = fmaxf(fmaxf(rmx[0], rmx[1]), fmaxf(rmx[2], rmx[3]));
    rmax = fmaxf(rmax, __shfl_xor(rmax, 16));    // quad-partner reduce: full row max
    rmax = fmaxf(rmax, __shfl_xor(rmax, 32));

    // deferred rescale (T13): 54 raw ~= 8 exp2-units -> p bounded by 2^8
    int ok = (rmax <= mrow + 54.0f) ? 1 : 0;
    if (!__all(ok)) {
      float mnew = fmaxf(mrow, rmax);
      float alpha = EXP2((mrow - mnew) * cs);    // m=-inf -> alpha=0 first iter
      mrow = mnew;
      lrow *= alpha;
      float av[4];
#pragma unroll
      for (int r = 0; r < 4; r++) av[r] = __shfl(alpha, quad * 4 + r);  // acc_o row = quad*4+r
#pragma unroll
      for (int di = 0; di < 6; di++)
#pragma unroll
        for (int r = 0; r < 4; r++) acc_o[di][r] *= av[r];
    }

    const float nmc = -mrow * cs;
    float rs[4] = {0.f, 0.f, 0.f, 0.f};
    unsigned int pk[8][2];                       // packed bf16x2: tile ni, s pairs
#pragma unroll
    for (int ni = 0; ni < 8; ni++) {
      if (ni <= nlim) {
        float p0 = EXP2(fmaf(sacc[ni][0], cs, nmc));   // masked: exp2(-inf)=0
        float p1 = EXP2(fmaf(sacc[ni][1], cs, nmc));
        float p2 = EXP2(fmaf(sacc[ni][2], cs, nmc));
        float p3 = EXP2(fmaf(sacc[ni][3], cs, nmc));
        rs[0] += p0; rs[1] += p1; rs[2] += p2; rs[3] += p3;
        pk[ni][0] = cvtpk(p0, p1);
        pk[ni][1] = cvtpk(p2, p3);
      } else {
        pk[ni][0] = 0u; pk[ni][1] = 0u;
      }
    }
    lrow += (rs[0] + rs[1]) + (rs[2] + rs[3]);   // per-lane partial; reduce at end

    __syncthreads();                 // drains vmcnt(0): Vsm ready

    // ---- O += P V : A-fragment built in-register via 2-stage butterfly ----
    // target quad q' needs s-chunk q'*8..q'*8+7 of the 32-s chunk kc:
    //   q0 <- {q0.a, q1.a}; q1 <- {q2.a, q3.a}; q2 <- {q0.b, q1.b}; q3 <- {q2.b, q3.b}
    // (a = tile 2kc, b = tile 2kc+1; each source quad holds 2 dwords = 4 s-values)
#pragma unroll
    for (int kc = 0; kc < 4; kc++) {
      if (kc <= klim) {
        const unsigned int a0 = pk[2 * kc][0], a1 = pk[2 * kc][1];
        const unsigned int b0 = pk[2 * kc + 1][0], b1 = pk[2 * kc + 1][1];
        // stage 1 (xor 32): quads 0,1 receive partner's a; quads 2,3 receive partner's b
        const unsigned int s0w = (quad < 2) ? b0 : a0;
        const unsigned int s1w = (quad < 2) ? b1 : a1;
        const unsigned int u0 = (unsigned int)__shfl_xor((int)s0w, 32);
        const unsigned int u1 = (unsigned int)__shfl_xor((int)s1w, 32);
        // stage 2 (xor 16): quads 0,3 forward u; quad 1 sends own a, quad 2 sends own b
        const unsigned int t0w = (quad == 0 || quad == 3) ? u0 : ((quad == 1) ? a0 : b0);
        const unsigned int t1w = (quad == 0 || quad == 3) ? u1 : ((quad == 1) ? a1 : b1);
        const unsigned int r0 = (unsigned int)__shfl_xor((int)t0w, 16);
        const unsigned int r1 = (unsigned int)__shfl_xor((int)t1w, 16);
        // assemble per-quad: q0:{a,r} q1:{r,u} q2:{u,r} q3:{r,b}
        union { unsigned int w[4]; bf16x8 v; } ap;
        ap.w[0] = (quad == 0) ? a0 : ((quad == 2) ? u0 : r0);
        ap.w[1] = (quad == 0) ? a1 : ((quad == 2) ? u1 : r1);
        ap.w[2] = (quad == 0) ? r0 : ((quad == 1) ? u0 : ((quad == 2) ? r0 : b0));
        ap.w[3] = (quad == 0) ? r1 : ((quad == 1) ? u1 : ((quad == 2) ? r1 : b1));
#pragma unroll
        for (int di = 0; di < 6; di++) {
          // read swizzle matches the pre-swizzled source: chunk ^= (row&7), row&7 == l16&7
          bf16x8 bv = *(const bf16x8*)&Vsm[(di * 16 + l16) * 128 +
                                           (((kc * 4 + quad) ^ (l16 & 7)) << 3)];
          acc_o[di] = __builtin_amdgcn_mfma_f32_16x16x32_bf16(ap.v, bv, acc_o[di], 0, 0, 0);
        }
      }
    }
  }

  // ---- epilogue: reduce l across quad-partners, normalize, store ----
  lrow += __shfl_xor(lrow, 16);
  lrow += __shfl_xor(lrow, 32);              // lane holds full sum of its q-row
  float linv = 1.f / lrow;
  float lv[4];
#pragma unroll
  for (int r = 0; r < 4; r++) lv[r] = __shfl(linv, quad * 4 + r);
#pragma unroll
  for (int r = 0; r < 4; r++) {
    int t = qw0 + quad * 4 + r;
#pragma unroll
    for (int di = 0; di < 6; di++) {
      int d = di * 16 + l16;
      y[(b * Tz + t) * Cz + h * Dz + d] = f2bf(acc_o[di][r] * lv[r]);
    }
  }
}

// ---- workspace layout (bytes) ----
#define OFF_XB   0u
#define OFF_WAT  12582912u            // 8192*768*2
#define OFF_WPT  16121856u            // + 2304*768*2
#define OFF_QKV  17301504u            // + 768*768*2
#define OFF_Y    55050240u            // + 3*64*1024*96*2

extern "C" void kernel_launch(void* const* d_in, const int* in_sizes, int n_in,
                              void* d_out, int out_size, void* d_ws, size_t ws_size,
                              hipStream_t stream) {
  const float* x  = (const float*)d_in[0];
  const float* Wa = (const float*)d_in[1];
  const float* Wp = (const float*)d_in[2];
  float* out = (float*)d_out;
  uint8_t* ws = (uint8_t*)d_ws;
  unsigned short* xb  = (unsigned short*)(ws + OFF_XB);
  unsigned short* Wat = (unsigned short*)(ws + OFF_WAT);
  unsigned short* Wpt = (unsigned short*)(ws + OFF_WPT);
  unsigned short* qkv = (unsigned short*)(ws + OFF_QKV);
  unsigned short* y   = (unsigned short*)(ws + OFF_Y);

  cast_f32_bf16<<<6144, 256, 0, stream>>>(x, xb);
  transpose_cast<<<dim3(36, 12), 256, 0, stream>>>(Wa, Wat, 768, 2304);
  transpose_cast<<<dim3(12, 12), 256, 0, stream>>>(Wp, Wpt, 768, 768);
  gemm128<0><<<dim3(64, 18), 256, 0, stream>>>(xb, Wat, qkv, nullptr);
  attn<<<dim3(64, 16), 256, 0, stream>>>(qkv, y);
  gemm128<1><<<dim3(64, 6), 256, 0, stream>>>(y, Wpt, nullptr, out);
}

// Round 8
// 200.601 us; speedup vs baseline: 1.0845x; 1.0236x over previous
//
#include <hip/hip_runtime.h>
#include <stdint.h>

// ---- problem constants ----
#define Bz 8
#define Tz 1024
#define Cz 768
#define Hz 8
#define Dz 96
#define BHz 64            // Bz*Hz
#define Kz 768

typedef __bf16 bf16x8 __attribute__((ext_vector_type(8)));
typedef unsigned short u16x8 __attribute__((ext_vector_type(8)));
typedef float f32x4 __attribute__((ext_vector_type(4)));

__device__ __forceinline__ unsigned short f2bf(float f) {
  union { float f; unsigned int u; } v; v.f = f;
  unsigned int u = v.u;
  return (unsigned short)((u + 0x7fffu + ((u >> 16) & 1u)) >> 16);
}

// pack two f32 -> one dword of 2x bf16 (lo=a, hi=b); gfx950 hw instr (guide T12)
__device__ __forceinline__ unsigned int cvtpk(float a, float b) {
  unsigned int r;
  asm("v_cvt_pk_bf16_f32 %0, %1, %2" : "=v"(r) : "v"(a), "v"(b));
  return r;
}

#if defined(__has_builtin)
#if __has_builtin(__builtin_amdgcn_exp2f)
#define EXP2(x) __builtin_amdgcn_exp2f(x)
#endif
#endif
#ifndef EXP2
#define EXP2(x) __expf((x) * 0.6931471805599453f)
#endif

// async global->LDS, 16B per lane; LDS dest must be wave-uniform base (+lane*16 implicit)
typedef const __attribute__((address_space(1))) void* gas_ptr;
typedef __attribute__((address_space(3))) void* las_ptr;
__device__ __forceinline__ void gl16(const void* g, void* l) {
  __builtin_amdgcn_global_load_lds((gas_ptr)g, (las_ptr)l, 16, 0, 0);
}

// ---- fused prep: cast x->bf16 (blocks 0..6143), transpose Wa (..6575), Wp (..6719) ----
__global__ __launch_bounds__(256) void prep(const float* __restrict__ x,
                                            unsigned short* __restrict__ xb,
                                            const float* __restrict__ Wa,
                                            unsigned short* __restrict__ Wat,
                                            const float* __restrict__ Wp,
                                            unsigned short* __restrict__ Wpt) {
  __shared__ unsigned short t[64][72];
  const int bid = blockIdx.x;
  const int tid = threadIdx.x;
  if (bid < 6144) {
    int i = (bid * 256 + tid) * 4;
    float4 v = *(const float4*)(x + i);
    union { unsigned short s[4]; uint2 u; } o;
    o.s[0] = f2bf(v.x); o.s[1] = f2bf(v.y); o.s[2] = f2bf(v.z); o.s[3] = f2bf(v.w);
    *(uint2*)(xb + i) = o.u;
    return;
  }
  const float* in; unsigned short* out; int R, Cc, bx, by;
  if (bid < 6576) { int q = bid - 6144; in = Wa; out = Wat; R = 768; Cc = 2304; bx = (q % 36) * 64; by = (q / 36) * 64; }
  else            { int q = bid - 6576; in = Wp; out = Wpt; R = 768; Cc = 768;  bx = (q % 12) * 64; by = (q / 12) * 64; }
#pragma unroll
  for (int i = 0; i < 16; i++) {
    int idx = tid + i * 256;
    int r = idx >> 6, c = idx & 63;
    t[c][r] = f2bf(in[(by + r) * Cc + bx + c]);
  }
  __syncthreads();
#pragma unroll
  for (int i = 0; i < 16; i++) {
    int idx = tid + i * 256;
    int r = idx >> 6, c = idx & 63;
    out[(bx + r) * R + by + c] = t[r][c];
  }
}

// ---- 128x128 MFMA bf16 GEMM, BK=64, global_load_lds + both-sides swizzle ----
// Natural block mapping (bm=bx, bn=by): round-robin dispatch makes A-panels L2-resident
// per XCD (round-4 lesson: do NOT swizzle blockIdx here).
// BK=64: 12 K-iterations (half the barrier/vmcnt-drain count of BK=32).
// LDS rows are 128 B => naive read = 16-way bank conflict; fix per rule 21:
// pre-swizzle the GLOBAL source chunk (c ^ row&7 -> lane-constant (lane&7)^(lane>>3)),
// gl16 writes linearly, fragment read XORs its chunk with l16&7 -> 2 lanes/bank (free).
// MODE 0: epilogue scatters bf16 into qkv: Q,K as [which][64][1024][96];
//         V third written TRANSPOSED as [64][96][1024] (V^T).
// MODE 1: epilogue writes fp32 C[M][768]
template <int MODE>
__global__ __launch_bounds__(256)
void gemm128(const unsigned short* __restrict__ A,
             const unsigned short* __restrict__ Bt,
             unsigned short* __restrict__ obf,
             float* __restrict__ of32) {
  __shared__ unsigned short Asm[128 * 64];  // 16 KB, linear (gl16 dest), source-swizzled
  __shared__ unsigned short Bsm[128 * 64];
  const int tid = threadIdx.x;
  const int wave = tid >> 6, lane = tid & 63;
  const int quad = lane >> 4, l16 = lane & 15;
  const int bm = blockIdx.x, bn = blockIdx.y;
  const int wm = (wave >> 1) * 64, wn = (wave & 1) * 64;

  f32x4 zero = {0.f, 0.f, 0.f, 0.f};
  f32x4 acc[4][4];
#pragma unroll
  for (int i = 0; i < 4; i++)
#pragma unroll
    for (int j = 0; j < 4; j++) acc[i][j] = zero;

  // staging: issue (wave,g) covers rows g*32 + wave*8 .. +7; lane -> row +(lane>>3),
  // 16B chunk (lane&7) pre-swizzled by row&7 == lane>>3 (g*32, wave*8 are 0 mod 8)
  const int srow = lane >> 3;
  const int sch = (lane & 7) ^ srow;            // lane-constant swizzled source chunk
  const unsigned short* Ag[4];
  const unsigned short* Bg[4];
#pragma unroll
  for (int g = 0; g < 4; g++) {
    Ag[g] = A + (size_t)(bm * 128 + g * 32 + wave * 8 + srow) * Kz + sch * 8;
    Bg[g] = Bt + (size_t)(bn * 128 + g * 32 + wave * 8 + srow) * Kz + sch * 8;
  }

  for (int k0 = 0; k0 < Kz; k0 += 64) {
    __syncthreads();                 // WAR: previous frag reads done
#pragma unroll
    for (int g = 0; g < 4; g++) {
      gl16(Ag[g] + k0, &Asm[(g * 32 + wave * 8) * 64]);
      gl16(Bg[g] + k0, &Bsm[(g * 32 + wave * 8) * 64]);
    }
    __syncthreads();                 // drains vmcnt(0) then barrier
#pragma unroll
    for (int kk = 0; kk < 2; kk++) {
      const int rc = (((kk * 4 + quad) ^ (l16 & 7)) << 3);   // swizzled read chunk
      bf16x8 af[4], bfr[4];
#pragma unroll
      for (int mi = 0; mi < 4; mi++)
        af[mi] = *(const bf16x8*)&Asm[(wm + mi * 16 + l16) * 64 + rc];
#pragma unroll
      for (int ni = 0; ni < 4; ni++)
        bfr[ni] = *(const bf16x8*)&Bsm[(wn + ni * 16 + l16) * 64 + rc];
#pragma unroll
      for (int mi = 0; mi < 4; mi++)
#pragma unroll
        for (int ni = 0; ni < 4; ni++)
          acc[mi][ni] = __builtin_amdgcn_mfma_f32_16x16x32_bf16(af[mi], bfr[ni], acc[mi][ni], 0, 0, 0);
    }
  }

#pragma unroll
  for (int mi = 0; mi < 4; mi++) {
    int row = bm * 128 + wm + mi * 16 + quad * 4;
    if (MODE == 0) {
      int b = row >> 10;
      int t = row & 1023;
#pragma unroll
      for (int ni = 0; ni < 4; ni++) {
        int col = bn * 128 + wn + ni * 16 + l16;
        int which = col / 768;        // wave-uniform per fragment (16 | 768)
        int cc = col - which * 768;
        int h = cc / 96;
        int d = cc - h * 96;
        if (which == 2) {
          // V^T layout: [bh][d][t]; r increments t -> 4 contiguous bf16 = one 8B store
          int base = ((2 * 64 + b * 8 + h) * 96 + d) * 1024 + t;
          union { unsigned short s[4]; uint2 u; } o;
#pragma unroll
          for (int r = 0; r < 4; r++) o.s[r] = f2bf(acc[mi][ni][r]);
          *(uint2*)(obf + base) = o.u;
        } else {
          int base = ((which * 64 + b * 8 + h) * 1024 + t) * 96 + d;
#pragma unroll
          for (int r = 0; r < 4; r++) obf[base + r * 96] = f2bf(acc[mi][ni][r]);
        }
      }
    } else {
#pragma unroll
      for (int ni = 0; ni < 4; ni++) {
        int col = bn * 128 + wn + ni * 16 + l16;
#pragma unroll
        for (int r = 0; r < 4; r++) of32[(row + r) * 768 + col] = acc[mi][ni][r];
      }
    }
  }
}

// ---- flash attention: 1 block = (b,h) x 64 q-rows; 4 waves x 16 rows; BS=128 ----
// (validated round 7, unchanged) swapped-QK^T in-register-P structure; V staged via
// global_load_lds direct into linear Vsm with rule-21 both-sides swizzle.
__global__ __launch_bounds__(256, 4)
void attn(const unsigned short* __restrict__ qkv, unsigned short* __restrict__ y) {
  const int bh = blockIdx.x;
  const int by = blockIdx.y;
  const int q0 = (15 - by) * 64;           // heavy tiles dispatch first, class-balanced
  const int tid = threadIdx.x;
  const int wave = tid >> 6, lane = tid & 63;
  const int quad = lane >> 4, l16 = lane & 15;
  const int qw0 = q0 + wave * 16;          // this wave's 16 q-rows (1 m-tile)
  const int b = bh >> 3, h = bh & 7;

  const unsigned short* Qh = qkv + bh * Tz * Dz;
  const unsigned short* Kh = qkv + (BHz + bh) * Tz * Dz;
  const unsigned short* Vt = qkv + 2 * BHz * Tz * Dz + bh * Dz * Tz;  // V^T [d][t]

  __shared__ unsigned short Vsm[96 * 128];       // linear (gl16 dest), source-swizzled

  bf16x8 aq[3];                            // Q as MFMA B-operand: lane holds Q[q=l16][d..]
#pragma unroll
  for (int kd = 0; kd < 3; kd++)
    aq[kd] = *(const bf16x8*)(Qh + (qw0 + l16) * Dz + kd * 32 + quad * 8);

  f32x4 zero = {0.f, 0.f, 0.f, 0.f};
  f32x4 acc_o[6];
#pragma unroll
  for (int i = 0; i < 6; i++) acc_o[i] = zero;
  const float NEG = -__builtin_inff();
  float mrow = NEG, lrow = 0.f;            // scalar/lane: state of q-row (qw0 + l16)
  const float cs = 0.14724538519872735f;   // (1/sqrt(96)) * log2(e): exp2-domain softmax
  const int t_abs = qw0 + l16;             // this lane's q-row

  // V staging map (per wave-issue g): rows wave*24 + g*4 .. +3, lane -> row +(lane>>4),
  // chunk lane&15; global source chunk pre-swizzled: c ^ (row&7)
  const int vrow = wave * 24 + (lane >> 4);      // row of THIS lane at g=0 (g adds 4)
  const int vch = lane & 15;

  const int s_last = (q0 >> 7) << 7;       // floor(q0/128)*128
  for (int s0 = 0; s0 <= s_last; s0 += 128) {
    __syncthreads();                 // WAR: prior iter's Vsm reads done
    // ---- async V^T tile -> LDS (drains at the pre-PV barrier; hides under QK^T) ----
#pragma unroll
    for (int g = 0; g < 6; g++) {
      const int row = vrow + g * 4;
      gl16(Vt + row * Tz + s0 + ((vch ^ (row & 7)) << 3),
           &Vsm[(wave * 24 + g * 4) * 128]);
    }

    const int srem = qw0 + 15 - s0;              // >= 15 always; srem%16==15
    const int nlim = min(7, srem >> 4);          // last 16-wide s tile with unmasked cols
    const int klim = min(3, srem >> 5);          // last 32-wide PV k chunk

    // ---- S^T = K Q^T (swapped operands; lane holds S[s=quad*4+r][q=l16]) ----
    f32x4 sacc[8];
#pragma unroll
    for (int ni = 0; ni < 8; ni++) {
      if (ni <= nlim) {
        sacc[ni] = zero;
#pragma unroll
        for (int kd = 0; kd < 3; kd++) {
          bf16x8 bk = *(const bf16x8*)(Kh + (s0 + ni * 16 + l16) * Dz + kd * 32 + quad * 8);
          sacc[ni] = __builtin_amdgcn_mfma_f32_16x16x32_bf16(bk, aq[kd], sacc[ni], 0, 0, 0);
        }
      }
    }

    // ---- online softmax, fully in-register ----
    float rmx[4] = {NEG, NEG, NEG, NEG};         // 4 independent chains for ILP
#pragma unroll
    for (int ni = 0; ni < 8; ni++) {
      if (ni <= nlim) {
        // mask only tiles that straddle/cross the diagonal (wave-uniform test)
        if (s0 + ni * 16 + 15 > qw0) {
          const int s_base = s0 + ni * 16 + quad * 4;
#pragma unroll
          for (int r = 0; r < 4; r++)
            if (s_base + r > t_abs) sacc[ni][r] = NEG;
        }
#pragma unroll
        for (int r = 0; r < 4; r++) rmx[r] = fmaxf(rmx[r], sacc[ni][r]);
      }
    }
    float rmax = fmaxf(fmaxf(rmx[0], rmx[1]), fmaxf(rmx[2], rmx[3]));
    rmax = fmaxf(rmax, __shfl_xor(rmax, 16));    // quad-partner reduce: full row max
    rmax = fmaxf(rmax, __shfl_xor(rmax, 32));

    // deferred rescale (T13): 54 raw ~= 8 exp2-units -> p bounded by 2^8
    int ok = (rmax <= mrow + 54.0f) ? 1 : 0;
    if (!__all(ok)) {
      float mnew = fmaxf(mrow, rmax);
      float alpha = EXP2((mrow - mnew) * cs);    // m=-inf -> alpha=0 first iter
      mrow = mnew;
      lrow *= alpha;
      float av[4];
#pragma unroll
      for (int r = 0; r < 4; r++) av[r] = __shfl(alpha, quad * 4 + r);  // acc_o row = quad*4+r
#pragma unroll
      for (int di = 0; di < 6; di++)
#pragma unroll
        for (int r = 0; r < 4; r++) acc_o[di][r] *= av[r];
    }

    const float nmc = -mrow * cs;
    float rs[4] = {0.f, 0.f, 0.f, 0.f};
    unsigned int pk[8][2];                       // packed bf16x2: tile ni, s pairs
#pragma unroll
    for (int ni = 0; ni < 8; ni++) {
      if (ni <= nlim) {
        float p0 = EXP2(fmaf(sacc[ni][0], cs, nmc));   // masked: exp2(-inf)=0
        float p1 = EXP2(fmaf(sacc[ni][1], cs, nmc));
        float p2 = EXP2(fmaf(sacc[ni][2], cs, nmc));
        float p3 = EXP2(fmaf(sacc[ni][3], cs, nmc));
        rs[0] += p0; rs[1] += p1; rs[2] += p2; rs[3] += p3;
        pk[ni][0] = cvtpk(p0, p1);
        pk[ni][1] = cvtpk(p2, p3);
      } else {
        pk[ni][0] = 0u; pk[ni][1] = 0u;
      }
    }
    lrow += (rs[0] + rs[1]) + (rs[2] + rs[3]);   // per-lane partial; reduce at end

    __syncthreads();                 // drains vmcnt(0): Vsm ready

    // ---- O += P V : A-fragment built in-register via 2-stage butterfly ----
    // target quad q' needs s-chunk q'*8..q'*8+7 of the 32-s chunk kc:
    //   q0 <- {q0.a, q1.a}; q1 <- {q2.a, q3.a}; q2 <- {q0.b, q1.b}; q3 <- {q2.b, q3.b}
    // (a = tile 2kc, b = tile 2kc+1; each source quad holds 2 dwords = 4 s-values)
#pragma unroll
    for (int kc = 0; kc < 4; kc++) {
      if (kc <= klim) {
        const unsigned int a0 = pk[2 * kc][0], a1 = pk[2 * kc][1];
        const unsigned int b0 = pk[2 * kc + 1][0], b1 = pk[2 * kc + 1][1];
        // stage 1 (xor 32): quads 0,1 receive partner's a; quads 2,3 receive partner's b
        const unsigned int s0w = (quad < 2) ? b0 : a0;
        const unsigned int s1w = (quad < 2) ? b1 : a1;
        const unsigned int u0 = (unsigned int)__shfl_xor((int)s0w, 32);
        const unsigned int u1 = (unsigned int)__shfl_xor((int)s1w, 32);
        // stage 2 (xor 16): quads 0,3 forward u; quad 1 sends own a, quad 2 sends own b
        const unsigned int t0w = (quad == 0 || quad == 3) ? u0 : ((quad == 1) ? a0 : b0);
        const unsigned int t1w = (quad == 0 || quad == 3) ? u1 : ((quad == 1) ? a1 : b1);
        const unsigned int r0 = (unsigned int)__shfl_xor((int)t0w, 16);
        const unsigned int r1 = (unsigned int)__shfl_xor((int)t1w, 16);
        // assemble per-quad: q0:{a,r} q1:{r,u} q2:{u,r} q3:{r,b}
        union { unsigned int w[4]; bf16x8 v; } ap;
        ap.w[0] = (quad == 0) ? a0 : ((quad == 2) ? u0 : r0);
        ap.w[1] = (quad == 0) ? a1 : ((quad == 2) ? u1 : r1);
        ap.w[2] = (quad == 0) ? r0 : ((quad == 1) ? u0 : ((quad == 2) ? r0 : b0));
        ap.w[3] = (quad == 0) ? r1 : ((quad == 1) ? u1 : ((quad == 2) ? r1 : b1));
#pragma unroll
        for (int di = 0; di < 6; di++) {
          // read swizzle matches the pre-swizzled source: chunk ^= (row&7), row&7 == l16&7
          bf16x8 bv = *(const bf16x8*)&Vsm[(di * 16 + l16) * 128 +
                                           (((kc * 4 + quad) ^ (l16 & 7)) << 3)];
          acc_o[di] = __builtin_amdgcn_mfma_f32_16x16x32_bf16(ap.v, bv, acc_o[di], 0, 0, 0);
        }
      }
    }
  }

  // ---- epilogue: reduce l across quad-partners, normalize, store ----
  lrow += __shfl_xor(lrow, 16);
  lrow += __shfl_xor(lrow, 32);              // lane holds full sum of its q-row
  float linv = 1.f / lrow;
  float lv[4];
#pragma unroll
  for (int r = 0; r < 4; r++) lv[r] = __shfl(linv, quad * 4 + r);
#pragma unroll
  for (int r = 0; r < 4; r++) {
    int t = qw0 + quad * 4 + r;
#pragma unroll
    for (int di = 0; di < 6; di++) {
      int d = di * 16 + l16;
      y[(b * Tz + t) * Cz + h * Dz + d] = f2bf(acc_o[di][r] * lv[r]);
    }
  }
}

// ---- workspace layout (bytes) ----
#define OFF_XB   0u
#define OFF_WAT  12582912u            // 8192*768*2
#define OFF_WPT  16121856u            // + 2304*768*2
#define OFF_QKV  17301504u            // + 768*768*2
#define OFF_Y    55050240u            // + 3*64*1024*96*2

extern "C" void kernel_launch(void* const* d_in, const int* in_sizes, int n_in,
                              void* d_out, int out_size, void* d_ws, size_t ws_size,
                              hipStream_t stream) {
  const float* x  = (const float*)d_in[0];
  const float* Wa = (const float*)d_in[1];
  const float* Wp = (const float*)d_in[2];
  float* out = (float*)d_out;
  uint8_t* ws = (uint8_t*)d_ws;
  unsigned short* xb  = (unsigned short*)(ws + OFF_XB);
  unsigned short* Wat = (unsigned short*)(ws + OFF_WAT);
  unsigned short* Wpt = (unsigned short*)(ws + OFF_WPT);
  unsigned short* qkv = (unsigned short*)(ws + OFF_QKV);
  unsigned short* y   = (unsigned short*)(ws + OFF_Y);

  prep<<<6720, 256, 0, stream>>>(x, xb, Wa, Wat, Wp, Wpt);
  gemm128<0><<<dim3(64, 18), 256, 0, stream>>>(xb, Wat, qkv, nullptr);
  attn<<<dim3(64, 16), 256, 0, stream>>>(qkv, y);
  gemm128<1><<<dim3(64, 6), 256, 0, stream>>>(y, Wpt, nullptr, out);
}